// Round 16
// baseline (324.874 us; speedup 1.0000x reference)
//
#include <hip/hip_runtime.h>

// CIN fused kernel, round 14 (2nd resubmit; broker timeouts).
// Refutation ledger: r12 bare-barrier (-7us) killed L1-drift theory; r13
// 4m x 2n + per-step hA ds_reads (232us, MfmaUtil 40, conflicts 2x) killed
// the L2-throughput theory AND showed A-side must stay register-resident.
// Surviving model: 2 waves/SIMD (256 regs: acc 128 AGPR + 128 VGPR) half-
// exposes every B-load -> MfmaUtil 46% = 512/1248 cyc per step. Fix that
// was never validly tested: smaller acc. r11 failed because a 64-VGPR hard
// cap + 32 resident hreg + 32 transient Bf guaranteed spill. Correct
// geometry: wave = 2m x 2n -> acc[2][2] = 64 AGPR, hreg[2][4] = 32 VGPR
// RESIDENT, Bf transient 8; arch VGPR ~70-90, total ~135-155 <= 170 =
// 3 waves/SIMD budget via __launch_bounds__(256,3) (soft cap, real
// headroom -- not r11's knife edge). NB=8, 256 thr, grid 1024, 3 blk/CU.
// Per-CU matrix work unchanged; per-wave B traffic 1 KB/step.
// Kept invariants: ZERO-barrier K-loop (r4/r10), premask fprep (r11/r13
// verified), hreg-load-then-sync layer structure, literal reg indices.
// GEMM: M = B*16 (m = batch*16+d), N = 128, K = i*64+j (layer-0 sparse).
// Wave w: batches (w>>1)*4 .. +4 (2 m-tiles), n-tiles (w&1)*2 .. +2.

#define F0N 39
#define NB  8                                 // batches per block
#define NC16 156                              // K/16 per layer
#define LAYER_HALVES (NC16 * 4 * 64 * 8)      // 319488 f16 per layer

typedef _Float16 half8 __attribute__((ext_vector_type(8)));
typedef float f32x16 __attribute__((ext_vector_type(16)));

// ---- prep: swizzle filters into 32x32x16 B-fragment order, f16 ----
// fprep[l][c16][nt][lane][reg] = F_l[row(kg), nt*32 + (lane&31)],
// kg = c16*16 + (lane>>5)*8 + reg.
// Layer 0 PREMASKED: row = i*39+j (i=kg>>6, j=kg&63); value = 2*f0[row,n]
// if (j<39 && j>i) else 0 (triu mask + 2.0 scale baked in; verified).
__global__ void prep_kernel(const float* __restrict__ f0,
                            const float* __restrict__ f1,
                            const float* __restrict__ f2,
                            _Float16* __restrict__ fprep) {
    int blk  = blockIdx.x;            // l*NC16 + c16
    int l    = blk / NC16;
    int c16  = blk - l * NC16;
    int t    = threadIdx.x;
    int nt   = t >> 6;
    int lane = t & 63;
    int hf   = lane >> 5;
    int n    = nt * 32 + (lane & 31);
    const float* f = (l == 0) ? f0 : ((l == 1) ? f1 : f2);
    half8 v;
    #pragma unroll
    for (int reg = 0; reg < 8; ++reg) {
        int kg = c16 * 16 + hf * 8 + reg;
        float x;
        if (l == 0) {
            int fi = kg >> 6, fj = kg & 63;
            x = (fj < F0N && fj > fi) ? 2.0f * f[(fi * F0N + fj) * 128 + n] : 0.0f;
        } else {
            x = f[(size_t)kg * 128 + n];
        }
        v[reg] = (_Float16)x;
    }
    *(half8*)&fprep[(size_t)l * LAYER_HALVES + (((c16 * 4 + nt) * 64 + lane) << 3)] = v;
}

// One K=16 step (Q literal): 2 B-loads (this wave's n-pair), resident hreg,
// 4 MFMAs. Bf/Af transient.
#define FULL_STEP(Q)                                                          \
    do {                                                                      \
        const _Float16* bq = fpl + ((((size_t)(i * 4 + (Q)) * 4 + nh2) * 64 + lane) << 3); \
        half8 Bf0 = *(const half8*)bq;                                        \
        half8 Bf1 = *(const half8*)(bq + 512);                                \
        half8 Af0 = hreg[0][(Q)] * xv2[0];                                    \
        half8 Af1 = hreg[1][(Q)] * xv2[1];                                    \
        acc[0][0] = __builtin_amdgcn_mfma_f32_32x32x16_f16(Af0, Bf0, acc[0][0], 0, 0, 0); \
        acc[0][1] = __builtin_amdgcn_mfma_f32_32x32x16_f16(Af0, Bf1, acc[0][1], 0, 0, 0); \
        acc[1][0] = __builtin_amdgcn_mfma_f32_32x32x16_f16(Af1, Bf0, acc[1][0], 0, 0, 0); \
        acc[1][1] = __builtin_amdgcn_mfma_f32_32x32x16_f16(Af1, Bf1, acc[1][1], 0, 0, 0); \
    } while (0)

__global__ __launch_bounds__(256, 3) void cin_mfma(
    const float* __restrict__ xin,     // (B, 624) fp32
    const _Float16* __restrict__ fprep,
    const float* __restrict__ wnn,     // (256)
    const float* __restrict__ bnn,     // (1)
    float* __restrict__ out)           // (B)
{
    __shared__ _Float16 hT[NB * 16 * 72] __attribute__((aligned(16)));  // [nb][d][j pad72]
    __shared__ _Float16 xs[NB * 16 * 40] __attribute__((aligned(16)));  // [nb][d][i pad40]
    __shared__ float outacc[NB];

    const int t     = threadIdx.x;
    const int wave  = t >> 6;
    const int lane  = t & 63;
    const int hf    = lane >> 5;     // k-half within 16-chunk
    const int lane5 = lane & 31;
    const int dl    = lane & 15;     // d for A-side
    const int bt    = lane5 >> 4;    // A-side batch within 32-row tile
    const int mp4   = (wave >> 1) * 4;   // wave's first batch (local, 0 or 4)
    const int nh2   = (wave & 1) * 2;    // n-pair: global n-tiles nh2, nh2+1
    const int b0    = blockIdx.x * NB;

    // zero hT (j-pad must be 0: layer-0 h-runs read j up to 63)
    for (int u = t; u < NB * 16 * 72 / 8; u += 256) ((uint4*)hT)[u] = uint4{0, 0, 0, 0};
    if (t < NB) outacc[t] = 0.0f;
    __syncthreads();

    // stage x0 -> hT (layer-0 hidden, [nb][d][j=i]) and xs ([nb][d][i])
    for (int u = t; u < NB * F0N; u += 256) {
        int nb = u / F0N;
        int i  = u - nb * F0N;
        const float* src = xin + (size_t)(b0 + nb) * 624 + i * 16;
        #pragma unroll
        for (int q = 0; q < 4; ++q) {
            float4 v = *(const float4*)(src + q * 4);
            int d = q * 4;
            hT[(nb * 16 + d + 0) * 72 + i] = (_Float16)v.x;
            hT[(nb * 16 + d + 1) * 72 + i] = (_Float16)v.y;
            hT[(nb * 16 + d + 2) * 72 + i] = (_Float16)v.z;
            hT[(nb * 16 + d + 3) * 72 + i] = (_Float16)v.w;
            xs[(nb * 16 + d + 0) * 40 + i] = (_Float16)v.x;
            xs[(nb * 16 + d + 1) * 40 + i] = (_Float16)v.y;
            xs[(nb * 16 + d + 2) * 40 + i] = (_Float16)v.z;
            xs[(nb * 16 + d + 3) * 40 + i] = (_Float16)v.w;
        }
    }
    __syncthreads();

    for (int layer = 0; layer < 3; ++layer) {
        // lane's A rows: batch mp4 + mt*2 + bt, d = dl; 4 half8 per batch.
        half8 hreg[2][4];
        #pragma unroll
        for (int mt = 0; mt < 2; ++mt) {
            int base = ((mp4 + mt * 2 + bt) * 16 + dl) * 72 + hf * 8;
            #pragma unroll
            for (int r = 0; r < 4; ++r)
                hreg[mt][r] = *(const half8*)&hT[base + r * 16];
        }
        __syncthreads();   // h-regs loaded before epilogue may overwrite hT

        f32x16 acc[2][2];
        #pragma unroll
        for (int mt = 0; mt < 2; ++mt)
            #pragma unroll
            for (int nt = 0; nt < 2; ++nt)
                #pragma unroll
                for (int e = 0; e < 16; ++e) acc[mt][nt][e] = 0.0f;

        const _Float16* fpl = fprep + (size_t)layer * LAYER_HALVES;
        const int xrow0 = ((mp4 + bt) * 16 + dl) * 40;
        const int xrow1 = ((mp4 + 2 + bt) * 16 + dl) * 40;

        if (layer == 0) {
            // Premasked sparse: q0 live i<15, q1 live i<31, q2 live i<38,
            // q3 dead (all-zero filter rows, never read).
            _Float16 xv2[2];
            for (int i = 0; i < 16; ++i) {
                xv2[0] = xs[xrow0 + i];
                xv2[1] = xs[xrow1 + i];
                if (i < 15) FULL_STEP(0);
                FULL_STEP(1);
                FULL_STEP(2);
            }
            for (int i = 16; i < 32; ++i) {
                xv2[0] = xs[xrow0 + i];
                xv2[1] = xs[xrow1 + i];
                if (i < 31) FULL_STEP(1);
                FULL_STEP(2);
            }
            for (int i = 32; i < 38; ++i) {
                xv2[0] = xs[xrow0 + i];
                xv2[1] = xs[xrow1 + i];
                FULL_STEP(2);
            }
        } else {
            _Float16 xv2[2];
            for (int i = 0; i < F0N; ++i) {
                xv2[0] = xs[xrow0 + i];
                xv2[1] = xs[xrow1 + i];
                FULL_STEP(0);
                FULL_STEP(1);
                FULL_STEP(2);
                FULL_STEP(3);
            }
        }

        // ---- epilogue ----
        // C/D layout: col n = gnt*32 + lane5; row = (reg&3)+8*(reg>>2)+4*hf;
        // batch_in_tile = reg>>3, d = (reg&3) + 8*((reg>>2)&1) + 4*hf.
        const int catbase = (layer == 2) ? 128 : ((layer == 0) ? -64 : 0);
        #pragma unroll
        for (int mt = 0; mt < 2; ++mt) {
            const int nb0 = mp4 + mt * 2;
            float cm0 = 0.0f, cm1 = 0.0f;
            #pragma unroll
            for (int nt = 0; nt < 2; ++nt) {
                const int gnt = nh2 + nt;      // global n-tile 0..3
                float r[16];
                #pragma unroll
                for (int reg = 0; reg < 16; ++reg)
                    r[reg] = fmaxf(acc[mt][nt][reg], 0.0f);
                if (layer < 2 && gnt < 2) {    // next hidden: cols 0..63
                    const int j = gnt * 32 + lane5;
                    #pragma unroll
                    for (int reg = 0; reg < 16; ++reg) {
                        int nb = nb0 + (reg >> 3);
                        int d  = (reg & 3) + 8 * ((reg >> 2) & 1) + 4 * hf;
                        hT[(nb * 16 + d) * 72 + j] = (_Float16)r[reg];
                    }
                }
                if (layer == 2 || gnt >= 2) {  // direct-out readout
                    const float w = 1.0f + wnn[catbase + gnt * 32 + lane5];
                    float s0 = ((r[0] + r[1]) + (r[2] + r[3])) +
                               ((r[4] + r[5]) + (r[6] + r[7]));
                    float s1 = ((r[8] + r[9]) + (r[10] + r[11])) +
                               ((r[12] + r[13]) + (r[14] + r[15]));
                    s0 += __shfl_xor(s0, 32, 64);  // combine hf halves
                    s1 += __shfl_xor(s1, 32, 64);
                    cm0 = fmaf(s0, w, cm0);
                    cm1 = fmaf(s1, w, cm1);
                }
            }
            #pragma unroll
            for (int sh = 16; sh >= 1; sh >>= 1) {
                cm0 += __shfl_xor(cm0, sh, 64);
                cm1 += __shfl_xor(cm1, sh, 64);
            }
            if (lane == 0 && (nh2 == 2 || layer == 2)) {
                atomicAdd(&outacc[nb0], cm0);
                atomicAdd(&outacc[nb0 + 1], cm1);
            }
        }
        __syncthreads();   // hT(next hidden) + outacc visible
    }

    if (t < NB) out[b0 + t] = outacc[t] + bnn[0];
}

extern "C" void kernel_launch(void* const* d_in, const int* in_sizes, int n_in,
                              void* d_out, int out_size, void* d_ws, size_t ws_size,
                              hipStream_t stream) {
    const float* xin = (const float*)d_in[0];
    const float* f0g = (const float*)d_in[1];
    const float* f1g = (const float*)d_in[2];
    const float* f2g = (const float*)d_in[3];
    const float* wnn = (const float*)d_in[4];
    const float* bnn = (const float*)d_in[5];
    float* out = (float*)d_out;
    _Float16* fprep = (_Float16*)d_ws;   // 3 * 319488 * 2 B = 1.83 MB

    prep_kernel<<<3 * NC16, 256, 0, stream>>>(f0g, f1g, f2g, fprep);

    const int B = in_sizes[0] / 624;     // 8192
    cin_mfma<<<B / NB, 256, 0, stream>>>(xin, fprep, wnn, bnn, out);
}

// Round 17
// 238.221 us; speedup vs baseline: 1.3637x; 1.3637x over previous
//
#include <hip/hip_runtime.h>

// CIN fused kernel, round 15: LDS B-sharing via T14 reg-staging
// (issue-early / write-late), r10 geometry.
// Model (fits ALL rounds): MFMA-busy constant ~94us; limiter is L1 vector-
// memory BW -- every wave pulls B through L1 independently (hits consume
// L1 BW too): r10 32KB/step/CU @ ~28B/cyc = 1100 cyc/step = measured 1248;
// r14's 24-vs-32 resident batches predicts 1.33x slower = measured 1.31x.
// Fix: share B across the block's 8 waves via LDS. r6-r9 staging failed
// because refill was issued BETWEEN barriers -> next __syncthreads
// vmcnt(0)-drained the just-issued prefetch (depth forced to 0), and the
// counted-vmcnt repair spilled via asm clobbers. T14 structure avoids both:
//   top of iter i: plain global loads of panel(i+1) -> 8 VGPRs/thread
//   compute i's 4 k-steps from bst[i&1] (~2000 cyc; loads land mid-way)
//   ds_write regs -> bst[(i+1)&1]  (implicit waitcnt; nothing left in
//   flight) ; ONE __syncthreads per i (zero drain, no asm, no clobbers).
// Double-buffer WAR+RAW closed by the single barrier. New per-step bound:
// max(MFMA 512, LDS ~280, L1 ~128 cyc) -> MFMA-bound.
// Geometry = proven r10: NB=32, 512 thr, wave = 2m x 4n, acc[2][4] =
// 128 AGPR, hreg[2][4] resident, launch_bounds(512,2), literal indices.
// Premask fprep (triu + 2.0 baked in; verified r11/r13/r14).
// LDS: hT 72KB + xs 40KB + bst 2x16KB + outacc = 147.6KB, 1 block/CU.

#define F0N 39
#define NB  32                                // batches per block
#define NC16 156                              // K/16 per layer
#define LAYER_HALVES (NC16 * 4 * 64 * 8)      // 319488 f16 per layer
#define IHALFS 8192                           // halfs per i-panel (4 steps x 4nt x 64 x 8)

typedef _Float16 half8 __attribute__((ext_vector_type(8)));
typedef float f32x16 __attribute__((ext_vector_type(16)));

// ---- prep: swizzle filters into 32x32x16 B-fragment order, f16 ----
// fprep[l][c16][nt][lane][reg] = F_l[row(kg), nt*32 + (lane&31)],
// kg = c16*16 + (lane>>5)*8 + reg.
// Layer 0 PREMASKED: row = i*39+j (i=kg>>6, j=kg&63); value = 2*f0[row,n]
// if (j<39 && j>i) else 0 (triu mask + 2.0 scale baked in; verified).
__global__ void prep_kernel(const float* __restrict__ f0,
                            const float* __restrict__ f1,
                            const float* __restrict__ f2,
                            _Float16* __restrict__ fprep) {
    int blk  = blockIdx.x;            // l*NC16 + c16
    int l    = blk / NC16;
    int c16  = blk - l * NC16;
    int t    = threadIdx.x;
    int nt   = t >> 6;
    int lane = t & 63;
    int hf   = lane >> 5;
    int n    = nt * 32 + (lane & 31);
    const float* f = (l == 0) ? f0 : ((l == 1) ? f1 : f2);
    half8 v;
    #pragma unroll
    for (int reg = 0; reg < 8; ++reg) {
        int kg = c16 * 16 + hf * 8 + reg;
        float x;
        if (l == 0) {
            int fi = kg >> 6, fj = kg & 63;
            x = (fj < F0N && fj > fi) ? 2.0f * f[(fi * F0N + fj) * 128 + n] : 0.0f;
        } else {
            x = f[(size_t)kg * 128 + n];
        }
        v[reg] = (_Float16)x;
    }
    *(half8*)&fprep[(size_t)l * LAYER_HALVES + (((c16 * 4 + nt) * 64 + lane) << 3)] = v;
}

// One K=16 step (Q literal): Bf from LDS (lane-contiguous 16B, conflict-
// free), resident hreg, 8 MFMAs.
#define FULL_STEP_LS(Q)                                                       \
    do {                                                                      \
        half8 Bf[4];                                                          \
        _Pragma("unroll")                                                     \
        for (int nt = 0; nt < 4; ++nt)                                        \
            Bf[nt] = *(const half8*)&bcur[(((Q) * 4 + nt) * 64 + lane) << 3]; \
        half8 Af[2];                                                          \
        _Pragma("unroll")                                                     \
        for (int mt = 0; mt < 2; ++mt) Af[mt] = hreg[mt][(Q)] * xv2[mt];      \
        _Pragma("unroll")                                                     \
        for (int mt = 0; mt < 2; ++mt)                                        \
            _Pragma("unroll")                                                 \
            for (int nt = 0; nt < 4; ++nt)                                    \
                acc[mt][nt] = __builtin_amdgcn_mfma_f32_32x32x16_f16(         \
                    Af[mt], Bf[nt], acc[mt][nt], 0, 0, 0);                    \
    } while (0)

// issue global loads of panel IP into registers (consumed by STAGE_WRITE)
#define STAGE_LOAD(IP)                                                        \
    do {                                                                      \
        const uint4* g = (const uint4*)(fpl + (size_t)(IP) * IHALFS);         \
        s0 = g[t];                                                            \
        s1 = g[t + 512];                                                      \
    } while (0)

// write staged registers into LDS buffer (lane-contiguous 16B, no conflict)
#define STAGE_WRITE(BUFP)                                                     \
    do {                                                                      \
        ((uint4*)(BUFP))[t]       = s0;                                       \
        ((uint4*)(BUFP))[t + 512] = s1;                                       \
    } while (0)

__global__ __launch_bounds__(512, 2) void cin_mfma(
    const float* __restrict__ xin,     // (B, 624) fp32
    const _Float16* __restrict__ fprep,
    const float* __restrict__ wnn,     // (256)
    const float* __restrict__ bnn,     // (1)
    float* __restrict__ out)           // (B)
{
    __shared__ _Float16 hT[NB * 16 * 72] __attribute__((aligned(16)));  // [nb][d][j pad72]
    __shared__ _Float16 xs[NB * 16 * 40] __attribute__((aligned(16)));  // [nb][d][i pad40]
    __shared__ _Float16 bst[2][IHALFS] __attribute__((aligned(16)));    // B i-panel dbuf
    __shared__ float outacc[NB];

    const int t     = threadIdx.x;
    const int wave  = t >> 6;
    const int lane  = t & 63;
    const int hf    = lane >> 5;     // k-half within 16-chunk
    const int lane5 = lane & 31;
    const int dl    = lane & 15;     // d for A-side
    const int bt    = lane5 >> 4;    // A-side batch within 32-row tile
    const int wb0   = wave * 4;      // wave's first batch (local, 0..28)
    const int b0    = blockIdx.x * NB;

    // zero hT (j-pad must be 0: layer-0 h-runs read j up to 63)
    for (int u = t; u < NB * 16 * 72 / 8; u += 512) ((uint4*)hT)[u] = uint4{0, 0, 0, 0};
    if (t < NB) outacc[t] = 0.0f;
    __syncthreads();

    // stage x0 -> hT (layer-0 hidden, [nb][d][j=i]) and xs ([nb][d][i])
    for (int u = t; u < NB * F0N; u += 512) {
        int nb = u / F0N;
        int i  = u - nb * F0N;
        const float* src = xin + (size_t)(b0 + nb) * 624 + i * 16;
        #pragma unroll
        for (int q = 0; q < 4; ++q) {
            float4 v = *(const float4*)(src + q * 4);
            int d = q * 4;
            hT[(nb * 16 + d + 0) * 72 + i] = (_Float16)v.x;
            hT[(nb * 16 + d + 1) * 72 + i] = (_Float16)v.y;
            hT[(nb * 16 + d + 2) * 72 + i] = (_Float16)v.z;
            hT[(nb * 16 + d + 3) * 72 + i] = (_Float16)v.w;
            xs[(nb * 16 + d + 0) * 40 + i] = (_Float16)v.x;
            xs[(nb * 16 + d + 1) * 40 + i] = (_Float16)v.y;
            xs[(nb * 16 + d + 2) * 40 + i] = (_Float16)v.z;
            xs[(nb * 16 + d + 3) * 40 + i] = (_Float16)v.w;
        }
    }
    __syncthreads();

    for (int layer = 0; layer < 3; ++layer) {
        const _Float16* fpl = fprep + (size_t)layer * LAYER_HALVES;
        uint4 s0, s1;

        // prologue: issue panel-0 loads (overlap with hreg ds_reads)
        STAGE_LOAD(0);

        // lane's A rows: batch wb0 + mt*2 + bt, d = dl; 4 half8 per batch.
        half8 hreg[2][4];
        #pragma unroll
        for (int mt = 0; mt < 2; ++mt) {
            int base = ((wb0 + mt * 2 + bt) * 16 + dl) * 72 + hf * 8;
            #pragma unroll
            for (int r = 0; r < 4; ++r)
                hreg[mt][r] = *(const half8*)&hT[base + r * 16];
        }
        __syncthreads();   // h-regs loaded (epilogue of prev layer done)

        STAGE_WRITE(bst[0]);   // panel 0 -> buf0 (waits its loads)
        __syncthreads();       // buf0 visible to all waves

        f32x16 acc[2][4];
        #pragma unroll
        for (int mt = 0; mt < 2; ++mt)
            #pragma unroll
            for (int nt = 0; nt < 4; ++nt)
                #pragma unroll
                for (int e = 0; e < 16; ++e) acc[mt][nt][e] = 0.0f;

        const int xrow0 = ((wb0 + bt) * 16 + dl) * 40;
        const int xrow1 = ((wb0 + 2 + bt) * 16 + dl) * 40;

        if (layer == 0) {
            // Premasked sparse: q0 live i<15, q1 live i<31, q2 live i<38,
            // q3 dead (all-zero filter rows, never read). 38 iterations.
            _Float16 xv2[2];
            for (int i = 0; i < 38; ++i) {
                const _Float16* bcur = bst[i & 1];
                _Float16* bnxt = bst[(i & 1) ^ 1];
                if (i < 37) STAGE_LOAD(i + 1);      // issue early
                xv2[0] = xs[xrow0 + i];
                xv2[1] = xs[xrow1 + i];
                if (i < 15) FULL_STEP_LS(0);
                if (i < 31) FULL_STEP_LS(1);
                if (i < 37) STAGE_WRITE(bnxt);      // write late (loads landed)
                FULL_STEP_LS(2);
                __syncthreads();                    // buf swap; zero drain
            }
        } else {
            _Float16 xv2[2];
            for (int i = 0; i < F0N; ++i) {
                const _Float16* bcur = bst[i & 1];
                _Float16* bnxt = bst[(i & 1) ^ 1];
                if (i < F0N - 1) STAGE_LOAD(i + 1); // issue early
                xv2[0] = xs[xrow0 + i];
                xv2[1] = xs[xrow1 + i];
                FULL_STEP_LS(0);
                FULL_STEP_LS(1);
                FULL_STEP_LS(2);
                if (i < F0N - 1) STAGE_WRITE(bnxt); // write late (loads landed)
                FULL_STEP_LS(3);
                __syncthreads();                    // buf swap; zero drain
            }
        }

        // ---- epilogue ----
        // C/D layout: col n = nt*32 + lane5; row = (reg&3) + 8*(reg>>2) + 4*hf;
        // batch_in_tile = reg>>3, d = (reg&3) + 8*((reg>>2)&1) + 4*hf.
        const int catbase = (layer == 2) ? 128 : ((layer == 0) ? -64 : 0);
        #pragma unroll
        for (int mt = 0; mt < 2; ++mt) {
            const int nb0 = wb0 + mt * 2;
            float cm0 = 0.0f, cm1 = 0.0f;
            #pragma unroll
            for (int nt = 0; nt < 4; ++nt) {
                float r[16];
                #pragma unroll
                for (int reg = 0; reg < 16; ++reg)
                    r[reg] = fmaxf(acc[mt][nt][reg], 0.0f);
                if (layer < 2 && nt < 2) {         // next hidden: cols 0..63
                    const int j = nt * 32 + lane5;
                    #pragma unroll
                    for (int reg = 0; reg < 16; ++reg) {
                        int nb = nb0 + (reg >> 3);
                        int d  = (reg & 3) + 8 * ((reg >> 2) & 1) + 4 * hf;
                        hT[(nb * 16 + d) * 72 + j] = (_Float16)r[reg];
                    }
                }
                if (layer == 2 || nt >= 2) {       // direct-out readout
                    const float w = 1.0f + wnn[catbase + nt * 32 + lane5];
                    float s0r = ((r[0] + r[1]) + (r[2] + r[3])) +
                                ((r[4] + r[5]) + (r[6] + r[7]));
                    float s1r = ((r[8] + r[9]) + (r[10] + r[11])) +
                                ((r[12] + r[13]) + (r[14] + r[15]));
                    s0r += __shfl_xor(s0r, 32, 64);  // combine hf halves
                    s1r += __shfl_xor(s1r, 32, 64);
                    cm0 = fmaf(s0r, w, cm0);
                    cm1 = fmaf(s1r, w, cm1);
                }
            }
            #pragma unroll
            for (int sh = 16; sh >= 1; sh >>= 1) {
                cm0 += __shfl_xor(cm0, sh, 64);
                cm1 += __shfl_xor(cm1, sh, 64);
            }
            if (lane == 0) {
                atomicAdd(&outacc[nb0], cm0);
                atomicAdd(&outacc[nb0 + 1], cm1);
            }
        }
        __syncthreads();   // hT(next hidden) + outacc visible
    }

    if (t < NB) out[b0 + t] = outacc[t] + bnn[0];
}

extern "C" void kernel_launch(void* const* d_in, const int* in_sizes, int n_in,
                              void* d_out, int out_size, void* d_ws, size_t ws_size,
                              hipStream_t stream) {
    const float* xin = (const float*)d_in[0];
    const float* f0g = (const float*)d_in[1];
    const float* f1g = (const float*)d_in[2];
    const float* f2g = (const float*)d_in[3];
    const float* wnn = (const float*)d_in[4];
    const float* bnn = (const float*)d_in[5];
    float* out = (float*)d_out;
    _Float16* fprep = (_Float16*)d_ws;   // 3 * 319488 * 2 B = 1.83 MB

    prep_kernel<<<3 * NC16, 256, 0, stream>>>(f0g, f1g, f2g, fprep);

    const int B = in_sizes[0] / 624;     // 8192
    cin_mfma<<<B / NB, 512, 0, stream>>>(xin, fprep, wnn, bnn, out);
}